// Round 15
// baseline (1019.300 us; speedup 1.0000x reference)
//
#include <hip/hip_runtime.h>
#include <stdint.h>

#define D_DIM 1024
#define H_DIM 4096
#define O_DIM 1024
#define E_NUM 12
#define TOPK 4
#define N_TOK 8192

#define PAIR_CAP 34304          // up to 268 tiles * 128

typedef __bf16 bf16x8 __attribute__((ext_vector_type(8)));
typedef float f32x4 __attribute__((ext_vector_type(4)));
typedef unsigned short u16x8 __attribute__((ext_vector_type(8)));

typedef __attribute__((address_space(3))) unsigned int lds_uint;
typedef __attribute__((address_space(1))) const unsigned int glob_uint;

static __device__ __forceinline__ unsigned short f2b(float f) {
  union { float f; unsigned u; } v; v.f = f;
  unsigned r = v.u + 0x7FFFu + ((v.u >> 16) & 1u);   // RNE
  return (unsigned short)(r >> 16);
}

static __device__ __forceinline__ void gload16(const void* g, void* l) {
  __builtin_amdgcn_global_load_lds((glob_uint*)g, (lds_uint*)l, 16, 0, 0);
}

// ---------------- x -> bf16 ----------------
__global__ __launch_bounds__(256) void cvt_x_kernel(const float* __restrict__ x,
                                                    unsigned short* __restrict__ xb) {
  int i = blockIdx.x * 256 + threadIdx.x;   // one thread = 8 elements
  const float4* p = reinterpret_cast<const float4*>(x);
  float4 a = p[2 * i], b = p[2 * i + 1];
  uint4 st;
  st.x = (unsigned)f2b(a.x) | ((unsigned)f2b(a.y) << 16);
  st.y = (unsigned)f2b(a.z) | ((unsigned)f2b(a.w) << 16);
  st.z = (unsigned)f2b(b.x) | ((unsigned)f2b(b.y) << 16);
  st.w = (unsigned)f2b(b.z) | ((unsigned)f2b(b.w) << 16);
  reinterpret_cast<uint4*>(xb)[i] = st;
}

// ------- transpose+convert: in [E][R][C] f32 -> out [E][C][R] bf16 -------
__global__ __launch_bounds__(256) void transpose_cvt_kernel(const float* __restrict__ in,
                                                            unsigned short* __restrict__ out,
                                                            int R, int C) {
  __shared__ float tile[64][33];
  int e = blockIdx.z;
  size_t base = (size_t)e * R * C;
  int c0 = blockIdx.x * 32, r0 = blockIdx.y * 64;
  int tx = threadIdx.x & 31, ty = threadIdx.x >> 5;   // 32 x 8
#pragma unroll
  for (int i = 0; i < 64; i += 8)
    tile[ty + i][tx] = in[base + (size_t)(r0 + ty + i) * C + (c0 + tx)];
  __syncthreads();
#pragma unroll
  for (int k = 0; k < 4; k++) {
    int c = ty + k * 8;
    unsigned lo = f2b(tile[2 * tx][c]);
    unsigned hi = f2b(tile[2 * tx + 1][c]);
    *reinterpret_cast<unsigned*>(&out[base + (size_t)(c0 + c) * R + r0 + 2 * tx]) =
        lo | (hi << 16);
  }
}

// ---------------- gw transpose: gwT[e][d] = gw[d*12+e] ----------------
__global__ __launch_bounds__(256) void gwt_kernel(const float* __restrict__ gw,
                                                  float* __restrict__ gwT) {
  int e = blockIdx.x;
#pragma unroll
  for (int i = 0; i < 4; i++) {
    int d = i * 256 + threadIdx.x;
    gwT[e * D_DIM + d] = gw[(size_t)d * E_NUM + e];
  }
}

// ---------------- gating: one wave per 4 tokens, no atomics ----------------
__global__ __launch_bounds__(256) void gating_kernel(const float* __restrict__ x,
                                                     const float* __restrict__ gwT,
                                                     const float* __restrict__ gb,
                                                     int* __restrict__ tk_e,
                                                     float* __restrict__ tk_w) {
  int wv = (blockIdx.x * 256 + threadIdx.x) >> 6;  // global wave id
  int lane = threadIdx.x & 63;
  int n0 = wv * 4;                                  // 4 tokens per wave
  if (n0 >= N_TOK) return;

  const float4* x4 = reinterpret_cast<const float4*>(x);
  const float4* g4 = reinterpret_cast<const float4*>(gwT);

  float acc[4][E_NUM];
#pragma unroll
  for (int t = 0; t < 4; t++)
#pragma unroll
    for (int e = 0; e < E_NUM; e++) acc[t][e] = 0.f;

#pragma unroll
  for (int i = 0; i < 4; i++) {
    float4 xv[4];
#pragma unroll
    for (int t = 0; t < 4; t++) xv[t] = x4[(size_t)(n0 + t) * 256 + i * 64 + lane];
#pragma unroll
    for (int e = 0; e < E_NUM; e++) {
      float4 g = g4[e * 256 + i * 64 + lane];
#pragma unroll
      for (int t = 0; t < 4; t++) {
        acc[t][e] += xv[t].x * g.x + xv[t].y * g.y + xv[t].z * g.z + xv[t].w * g.w;
      }
    }
  }

#pragma unroll
  for (int t = 0; t < 4; t++)
#pragma unroll
    for (int e = 0; e < E_NUM; e++) {
      float v = acc[t][e];
#pragma unroll
      for (int s = 32; s > 0; s >>= 1) v += __shfl_xor(v, s, 64);
      acc[t][e] = v;
    }

#pragma unroll
  for (int t = 0; t < 4; t++) {
    if (lane == t) {
      int n = n0 + t;
      float sc[E_NUM], sm[E_NUM];
      float mx = -1e30f;
#pragma unroll
      for (int e = 0; e < E_NUM; e++) { sc[e] = acc[t][e] + gb[e]; mx = fmaxf(mx, sc[e]); }
      float Z = 0.f;
#pragma unroll
      for (int e = 0; e < E_NUM; e++) { sm[e] = expf(sc[e] - mx); Z += sm[e]; }
      bool used[E_NUM];
#pragma unroll
      for (int e = 0; e < E_NUM; e++) used[e] = false;
      int eid[TOPK]; float p[TOPK]; float wsum = 0.f;
      for (int k = 0; k < TOPK; k++) {
        float best = -1e30f; int bi = 0;
        for (int e = 0; e < E_NUM; e++)
          if (!used[e] && sc[e] > best) { best = sc[e]; bi = e; }  // strict >: ties -> lowest idx
        used[bi] = true; eid[k] = bi; p[k] = sm[bi] / Z; wsum += p[k];
      }
      float inv = 1.f / (wsum + 1e-8f);
      for (int k = 0; k < TOPK; k++) {
        tk_e[n * TOPK + k] = eid[k];
        tk_w[n * TOPK + k] = p[k] * inv;
      }
    }
  }
}

// ------- hist_rank: per-block, per-expert stable ranks via ballot (no atomics) -------
__global__ __launch_bounds__(256) void hist_rank_kernel(const int* __restrict__ tk_e,
                                                        int* __restrict__ lr,
                                                        int* __restrict__ bc) {
  int blk = blockIdx.x, t = threadIdx.x;
  int n = blk * 256 + t;
  int4 te = reinterpret_cast<const int4*>(tk_e)[n];
  int lane = t & 63, w = t >> 6;
  __shared__ int wt[4][E_NUM];
  int r0 = 0, r1 = 0, r2 = 0, r3 = 0;
#pragma unroll
  for (int e = 0; e < E_NUM; e++) {
    int flag = (te.x == e) || (te.y == e) || (te.z == e) || (te.w == e);
    unsigned long long m = __ballot(flag);
    int rw = __popcll(m & ((1ull << lane) - 1ull));
    if (lane == 0) wt[w][e] = __popcll(m);
    if (te.x == e) r0 = rw;
    if (te.y == e) r1 = rw;
    if (te.z == e) r2 = rw;
    if (te.w == e) r3 = rw;
  }
  __syncthreads();
#pragma unroll
  for (int e = 0; e < E_NUM; e++) {
    int base = 0;
#pragma unroll
    for (int w2 = 0; w2 < 4; w2++)
      if (w2 < w) base += wt[w2][e];
    if (te.x == e) r0 += base;
    if (te.y == e) r1 += base;
    if (te.z == e) r2 += base;
    if (te.w == e) r3 += base;
  }
  int4 out; out.x = r0; out.y = r1; out.z = r2; out.w = r3;
  reinterpret_cast<int4*>(lr)[n] = out;
  if (t == 0) {
#pragma unroll
    for (int e = 0; e < E_NUM; e++)
      bc[blk * E_NUM + e] = wt[0][e] + wt[1][e] + wt[2][e] + wt[3][e];
  }
}

// ------- scan2: per-expert totals -> padded poff + per-block bases bb -------
__global__ __launch_bounds__(64) void scan2_kernel(const int* __restrict__ bc,
                                                   int* __restrict__ poff,
                                                   int* __restrict__ bb) {
  int t = threadIdx.x;
  __shared__ int cnte[E_NUM];
  __shared__ int spoff[E_NUM + 1];
  if (t < E_NUM) {
    int s = 0;
#pragma unroll
    for (int b = 0; b < 32; b++) s += bc[b * E_NUM + t];
    cnte[t] = s;
  }
  __syncthreads();
  if (t == 0) {
    int off = 0; spoff[0] = 0;
    for (int e = 0; e < E_NUM; e++) {
      off += ((cnte[e] + 127) >> 7) << 7;
      spoff[e + 1] = off;
    }
  }
  __syncthreads();
  if (t < E_NUM + 1) poff[t] = spoff[t];
  if (t < E_NUM) {
    int run = spoff[t];
    for (int b = 0; b < 32; b++) {
      bb[b * E_NUM + t] = run;
      run += bc[b * E_NUM + t];
    }
  }
}

__global__ __launch_bounds__(256) void fill_pairs_kernel(int* __restrict__ pt) {
  int i = blockIdx.x * 256 + threadIdx.x;
  if (i < PAIR_CAP) pt[i] = 0;
}

// ------- scatter2: pure writes at precomputed positions; lr slot becomes ip -------
__global__ __launch_bounds__(256) void scatter2_kernel(const int* __restrict__ tk_e,
                                                       int* __restrict__ lr_ip,
                                                       const int* __restrict__ bb,
                                                       int* __restrict__ pt) {
  int n = blockIdx.x * 256 + threadIdx.x;
  if (n >= N_TOK) return;
  int blk = n >> 8;
  int4 te = reinterpret_cast<const int4*>(tk_e)[n];
  int4 l4 = reinterpret_cast<const int4*>(lr_ip)[n];
  int p0 = bb[blk * E_NUM + te.x] + l4.x;
  int p1 = bb[blk * E_NUM + te.y] + l4.y;
  int p2 = bb[blk * E_NUM + te.z] + l4.z;
  int p3 = bb[blk * E_NUM + te.w] + l4.w;
  pt[p0] = n; pt[p1] = n; pt[p2] = n; pt[p3] = n;
  int4 ip; ip.x = p0; ip.y = p1; ip.z = p2; ip.w = p3;
  reinterpret_cast<int4*>(lr_ip)[n] = ip;     // overwrite ranks with positions
}

// =================== GEMMs: 128x128 tile, BK=64 (2x BK=32 sub-tiles) ===================
// Round-14 proven body. Change this round is HOST-side only: TPC=67/NCH=4 so the
// per-chunk L3 working set (w1t slice ~48MB + hbuf 70MB + xb 16MB) fits the 256MB
// Infinity Cache -> B-panel re-reads hit L3 instead of HBM (gemm1 FETCH was 505MB
// vs 112MB unique at TPC=134: L3 thrash).

// ---------------- GEMM1: h = relu(x[tok] @ W1_e + b1_e), bf16 out ----------------
__global__ __launch_bounds__(256, 4) void gemm1_kernel(
    const unsigned short* __restrict__ xb,    // [N][D] bf16
    const unsigned short* __restrict__ w1t,   // [E][H][D] bf16
    const float* __restrict__ b1,             // [E][H]
    const int* __restrict__ pair_token,
    const int* __restrict__ poff,
    unsigned short* __restrict__ hbuf,        // [TPC*128][H] bf16
    int tile0, int tpc) {
  __shared__ unsigned short As[2][128 * 32];
  __shared__ unsigned short Bs[2][128 * 32];
  // XCD-chunked bijective swizzle (nwg % 8 == 0); colb fastest within chunk
  int cpx = gridDim.x >> 3;
  int f = (blockIdx.x & 7) * cpx + (blockIdx.x >> 3);
  int colb = f & 31;                          // 0..31, fastest
  int tile = f >> 5;

  int t = tile0 + tile;
  int totTiles = poff[E_NUM] >> 7;
  if (t >= totTiles) return;
  int rowg0 = t << 7;
  int e = 0;
#pragma unroll
  for (int i = 1; i < E_NUM; i++) e += (rowg0 >= poff[i]);

  const int tid = threadIdx.x;
  const int lane = tid & 63, wave = tid >> 6;
  const int wm = wave >> 1, wn = wave & 1;
  const int fr = lane & 15, fgq = lane >> 4;

  const int srow = tid >> 2;                              // staging row 0..63
  const int skc = (((tid & 3) ^ ((srow >> 1) & 3)) << 3); // swizzled source chunk (elems)
  int tok0 = pair_token[rowg0 + srow];
  int tok1 = pair_token[rowg0 + 64 + srow];
  const unsigned short* a0 = xb + (size_t)tok0 * D_DIM + skc;
  const unsigned short* a1 = xb + (size_t)tok1 * D_DIM + skc;
  int n0 = colb << 7;
  const unsigned short* wb = w1t + (size_t)e * H_DIM * D_DIM;
  const unsigned short* b0p = wb + (size_t)(n0 + srow) * D_DIM + skc;
  const unsigned short* b1p = wb + (size_t)(n0 + 64 + srow) * D_DIM + skc;

  const int cswz = (fgq ^ ((fr >> 1) & 3)) << 3;
  int aoff[4], boff[4];
#pragma unroll
  for (int mf = 0; mf < 4; mf++) aoff[mf] = (wm * 64 + mf * 16 + fr) * 32 + cswz;
#pragma unroll
  for (int nf = 0; nf < 4; nf++) boff[nf] = (wn * 64 + nf * 16 + fr) * 32 + cswz;

  f32x4 acc[4][4];
#pragma unroll
  for (int i = 0; i < 4; i++)
#pragma unroll
    for (int j = 0; j < 4; j++) acc[i][j] = (f32x4){0.f, 0.f, 0.f, 0.f};

  for (int kt = 0; kt < D_DIM / 64; ++kt) {
    int k0 = kt * 64;
#pragma unroll
    for (int h = 0; h < 2; h++) {
      int kh = k0 + h * 32;
      gload16(a0 + kh, &As[h][tid * 8]);
      gload16(a1 + kh, &As[h][2048 + tid * 8]);
      gload16(b0p + kh, &Bs[h][tid * 8]);
      gload16(b1p + kh, &Bs[h][2048 + tid * 8]);
    }
    __syncthreads();
#pragma unroll
    for (int h = 0; h < 2; h++) {
      bf16x8 af[4], bq[4];
#pragma unroll
      for (int mf = 0; mf < 4; mf++)
        af[mf] = *reinterpret_cast<const bf16x8*>(&As[h][aoff[mf]]);
#pragma unroll
      for (int nf = 0; nf < 4; nf++)
        bq[nf] = *reinterpret_cast<const bf16x8*>(&Bs[h][boff[nf]]);
#pragma unroll
      for (int mf = 0; mf < 4; mf++)
#pragma unroll
        for (int nf = 0; nf < 4; nf++)
          acc[mf][nf] = __builtin_amdgcn_mfma_f32_16x16x32_bf16(af[mf], bq[nf], acc[mf][nf], 0, 0, 0);
    }
    __syncthreads();
  }

  int lrow0 = tile << 7;
#pragma unroll
  for (int nf = 0; nf < 4; nf++) {
    int col = n0 + wn * 64 + nf * 16 + fr;
    float bias = b1[e * H_DIM + col];
#pragma unroll
    for (int mf = 0; mf < 4; mf++) {
      int m = wm * 64 + mf * 16 + fgq * 4;
#pragma unroll
      for (int r = 0; r < 4; r++) {
        float v = fmaxf(acc[mf][nf][r] + bias, 0.f);
        hbuf[(size_t)(lrow0 + m + r) * H_DIM + col] = f2b(v);
      }
    }
  }
}

// ------- GEMM2: youts[z][pair] = h @ W2_e (+b2 on z==0), plain bf16 stores -------
__global__ __launch_bounds__(256, 4) void gemm2_kernel(
    const unsigned short* __restrict__ hbuf,  // [TPC*128][H] bf16
    const unsigned short* __restrict__ w2t,   // [E][O][H] bf16
    const float* __restrict__ b2,             // [E][O]
    const int* __restrict__ poff,
    unsigned short* __restrict__ youts,       // [nsplit][PAIR_CAP][O] bf16
    int tile0, int tpc, int nsplit) {
  __shared__ unsigned short As[2][128 * 32];
  __shared__ unsigned short Bs[2][128 * 32];
  // XCD-chunked swizzle; decode: colb fastest, then z, tile outermost.
  int cpx = gridDim.x >> 3;
  int f = (blockIdx.x & 7) * cpx + (blockIdx.x >> 3);
  int colb = f & 7;                           // 0..7, fastest
  int rest = f >> 3;
  int z = rest % nsplit;
  int tile = rest / nsplit;

  int t = tile0 + tile;
  int totTiles = poff[E_NUM] >> 7;
  if (t >= totTiles) return;
  int rowg0 = t << 7;
  int e = 0;
#pragma unroll
  for (int i = 1; i < E_NUM; i++) e += (rowg0 >= poff[i]);

  const int tid = threadIdx.x;
  const int lane = tid & 63, wave = tid >> 6;
  const int wm = wave >> 1, wn = wave & 1;
  const int fr = lane & 15, fgq = lane >> 4;
  const int kspan = H_DIM / nsplit;
  const int kbase = z * kspan;

  const int srow = tid >> 2;
  const int skc = (((tid & 3) ^ ((srow >> 1) & 3)) << 3);
  int lrowb = tile << 7;
  const unsigned short* a0 = hbuf + (size_t)(lrowb + srow) * H_DIM + kbase + skc;
  const unsigned short* a1 = hbuf + (size_t)(lrowb + 64 + srow) * H_DIM + kbase + skc;
  int n0 = colb << 7;
  const unsigned short* wb = w2t + (size_t)e * O_DIM * H_DIM;
  const unsigned short* b0p = wb + (size_t)(n0 + srow) * H_DIM + kbase + skc;
  const unsigned short* b1p = wb + (size_t)(n0 + 64 + srow) * H_DIM + kbase + skc;

  const int cswz = (fgq ^ ((fr >> 1) & 3)) << 3;
  int aoff[4], boff[4];
#pragma unroll
  for (int mf = 0; mf < 4; mf++) aoff[mf] = (wm * 64 + mf * 16 + fr) * 32 + cswz;
#pragma unroll
  for (int nf = 0; nf < 4; nf++) boff[nf] = (wn * 64 + nf * 16 + fr) * 32 + cswz;

  f32x4 acc[4][4];
#pragma unroll
  for (int i = 0; i < 4; i++)
#pragma unroll
    for (int j = 0; j < 4; j++) acc[i][j] = (f32x4){0.f, 0.f, 0.f, 0.f};

  for (int kt = 0; kt < kspan / 64; ++kt) {
    int k0 = kt * 64;
#pragma unroll
    for (int h = 0; h < 2; h++) {
      int kh = k0 + h * 32;
      gload16(a0 + kh, &As[h][tid * 8]);
      gload16(a1 + kh, &As[h][2048 + tid * 8]);
      gload16(b0p + kh, &Bs[h][tid * 8]);
      gload16(b1p + kh, &Bs[h][2048 + tid * 8]);
    }
    __syncthreads();
#pragma unroll
    for (int h = 0; h < 2; h++) {
      bf16x8 af[4], bq[4];
#pragma unroll
      for (int mf = 0; mf < 4; mf++)
        af[mf] = *reinterpret_cast<const bf16x8*>(&As[h][aoff[mf]]);
#pragma unroll
      for (int nf = 0; nf < 4; nf++)
        bq[nf] = *reinterpret_cast<const bf16x8*>(&Bs[h][boff[nf]]);
#pragma unroll
      for (int mf = 0; mf < 4; mf++)
#pragma unroll
        for (int nf = 0; nf < 4; nf++)
          acc[mf][nf] = __builtin_amdgcn_mfma_f32_16x16x32_bf16(af[mf], bq[nf], acc[mf][nf], 0, 0, 0);
    }
    __syncthreads();
  }

  size_t ybase = (size_t)z * PAIR_CAP;
#pragma unroll
  for (int nf = 0; nf < 4; nf++) {
    int col = n0 + wn * 64 + nf * 16 + fr;
    float bias = (z == 0) ? b2[e * O_DIM + col] : 0.f;   // bias counted once
#pragma unroll
    for (int mf = 0; mf < 4; mf++) {
      int m = wm * 64 + mf * 16 + fgq * 4;
#pragma unroll
      for (int r = 0; r < 4; r++) {
        float v = acc[mf][nf][r] + bias;
        youts[(ybase + rowg0 + m + r) * O_DIM + col] = f2b(v);
      }
    }
  }
}

// ------- reduce: out[n] = sum_k w_k * (y0[p_k] (+ y1[p_k])) -------
static __device__ __forceinline__ void acc8(float* a, const unsigned short* y, float wk) {
  u16x8 v = *reinterpret_cast<const u16x8*>(y);
#pragma unroll
  for (int j = 0; j < 8; j++)
    a[j] += wk * __uint_as_float((unsigned)v[j] << 16);
}

__global__ __launch_bounds__(256) void reduce_kernel(const unsigned short* __restrict__ youts,
                                                     const int* __restrict__ ip,
                                                     const float* __restrict__ tk_w,
                                                     float* __restrict__ out,
                                                     int nsplit) {
  int gid = blockIdx.x * 256 + threadIdx.x;      // N_TOK * 128 threads
  int n = gid >> 7;
  int c0 = (gid & 127) << 3;
  int4 p = reinterpret_cast<const int4*>(ip)[n];
  float4 w = reinterpret_cast<const float4*>(tk_w)[n];
  const size_t zoff = (size_t)PAIR_CAP * O_DIM;
  float a[8];
#pragma unroll
  for (int j = 0; j < 8; j++) a[j] = 0.f;
  {
    const unsigned short* y = youts + (size_t)p.x * O_DIM + c0;
    acc8(a, y, w.x);
    if (nsplit == 2) acc8(a, y + zoff, w.x);
  }
  {
    const unsigned short* y = youts + (size_t)p.y * O_DIM + c0;
    acc8(a, y, w.y);
    if (nsplit == 2) acc8(a, y + zoff, w.y);
  }
  {
    const unsigned short* y = youts + (size_t)p.z * O_DIM + c0;
    acc8(a, y, w.z);
    if (nsplit == 2) acc8(a, y + zoff, w.z);
  }
  {
    const unsigned short* y = youts + (size_t)p.w * O_DIM + c0;
    acc8(a, y, w.w);
    if (nsplit == 2) acc8(a, y + zoff, w.w);
  }
  float* orow = out + (size_t)n * O_DIM + c0;
  float4 o0; o0.x = a[0]; o0.y = a[1]; o0.z = a[2]; o0.w = a[3];
  float4 o1; o1.x = a[4]; o1.y = a[5]; o1.z = a[6]; o1.w = a[7];
  reinterpret_cast<float4*>(orow)[0] = o0;
  reinterpret_cast<float4*>(orow)[1] = o1;
}

extern "C" void kernel_launch(void* const* d_in, const int* in_sizes, int n_in,
                              void* d_out, int out_size, void* d_ws, size_t ws_size,
                              hipStream_t stream) {
  const float* x  = (const float*)d_in[0];
  const float* gw = (const float*)d_in[1];
  const float* gb = (const float*)d_in[2];
  const float* w1 = (const float*)d_in[3];
  const float* b1 = (const float*)d_in[4];
  const float* w2 = (const float*)d_in[5];
  const float* b2 = (const float*)d_in[6];
  float* out = (float*)d_out;

  char* ws = (char*)d_ws;
  size_t off = 0;
  auto alloc = [&](size_t bytes) -> void* {
    void* p = ws + off;
    off = (off + bytes + 255) & ~(size_t)255;
    return p;
  };
  unsigned short* xb   = (unsigned short*)alloc((size_t)N_TOK * D_DIM * 2);
  unsigned short* w1t  = (unsigned short*)alloc((size_t)E_NUM * H_DIM * D_DIM * 2);
  unsigned short* w2t  = (unsigned short*)alloc((size_t)E_NUM * O_DIM * H_DIM * 2);
  float* gwT  = (float*)alloc((size_t)E_NUM * D_DIM * 4);
  int*   tk_e = (int*)alloc((size_t)N_TOK * TOPK * 4);
  float* tk_w = (float*)alloc((size_t)N_TOK * TOPK * 4);
  int*   lr   = (int*)alloc((size_t)N_TOK * TOPK * 4);   // ranks, then pair positions (ip)
  int*   pt   = (int*)alloc((size_t)PAIR_CAP * 4);
  int*   bc   = (int*)alloc(32 * E_NUM * 4);
  int*   bb   = (int*)alloc(32 * E_NUM * 4);
  int*   poff = (int*)alloc(64);

  // L3-fit chunking: per-chunk working set (w1t slice + hbuf chunk + xb) < 256MB L3.
  const size_t HB67  = (size_t)67 * 128 * H_DIM * 2;    // 70 MB hbuf chunk
  const size_t YO    = (size_t)PAIR_CAP * O_DIM * 2;
  int TPC, NCH, NS;
  if (ws_size >= off + HB67 + 2 * YO + 1024)       { TPC = 67; NCH = 4; NS = 2; }
  else if (ws_size >= off + HB67 + YO + 1024)      { TPC = 67; NCH = 4; NS = 1; }
  else                                             { TPC = 34; NCH = 8; NS = 1; }
  unsigned short* hbuf  = (unsigned short*)alloc((size_t)TPC * 128 * H_DIM * 2);
  unsigned short* youts = (unsigned short*)alloc((size_t)NS * YO);
  if (off > ws_size) return;   // workspace too small: fail cleanly

  cvt_x_kernel<<<N_TOK * D_DIM / 8 / 256, 256, 0, stream>>>(x, xb);
  transpose_cvt_kernel<<<dim3(H_DIM / 32, D_DIM / 64, E_NUM), 256, 0, stream>>>(w1, w1t, D_DIM, H_DIM);
  transpose_cvt_kernel<<<dim3(O_DIM / 32, H_DIM / 64, E_NUM), 256, 0, stream>>>(w2, w2t, H_DIM, O_DIM);
  gwt_kernel<<<E_NUM, 256, 0, stream>>>(gw, gwT);
  gating_kernel<<<N_TOK / 16, 256, 0, stream>>>(x, gwT, gb, tk_e, tk_w);
  hist_rank_kernel<<<N_TOK / 256, 256, 0, stream>>>(tk_e, lr, bc);
  scan2_kernel<<<1, 64, 0, stream>>>(bc, poff, bb);
  fill_pairs_kernel<<<(PAIR_CAP + 255) / 256, 256, 0, stream>>>(pt);
  scatter2_kernel<<<N_TOK / 256, 256, 0, stream>>>(tk_e, lr, bb, pt);

  int nTiles = (N_TOK * TOPK + 12 * 127) / 128;   // upper bound; per-launch guard trims
  for (int c = 0; c < NCH; c++) {
    int tile0 = c * TPC;
    gemm1_kernel<<<dim3((H_DIM / 128) * TPC), 256, 0, stream>>>(xb, w1t, b1, pt, poff, hbuf, tile0, TPC);
    gemm2_kernel<<<dim3((O_DIM / 128) * TPC * NS), 256, 0, stream>>>(hbuf, w2t, b2, poff, youts, tile0, TPC, NS);
  }
  (void)nTiles;
  reduce_kernel<<<N_TOK * (O_DIM / 8) / 256, 256, 0, stream>>>(youts, lr, tk_w, out, NS);
}

// Round 16
// 983.934 us; speedup vs baseline: 1.0359x; 1.0359x over previous
//
#include <hip/hip_runtime.h>
#include <stdint.h>

#define D_DIM 1024
#define H_DIM 4096
#define O_DIM 1024
#define E_NUM 12
#define TOPK 4
#define N_TOK 8192

#define PAIR_CAP 34304          // up to 268 tiles * 128

typedef __bf16 bf16x8 __attribute__((ext_vector_type(8)));
typedef float f32x4 __attribute__((ext_vector_type(4)));
typedef unsigned short u16x8 __attribute__((ext_vector_type(8)));

typedef __attribute__((address_space(3))) unsigned int lds_uint;
typedef __attribute__((address_space(1))) const unsigned int glob_uint;

static __device__ __forceinline__ unsigned short f2b(float f) {
  union { float f; unsigned u; } v; v.f = f;
  unsigned r = v.u + 0x7FFFu + ((v.u >> 16) & 1u);   // RNE
  return (unsigned short)(r >> 16);
}

static __device__ __forceinline__ void gload16(const void* g, void* l) {
  __builtin_amdgcn_global_load_lds((glob_uint*)g, (lds_uint*)l, 16, 0, 0);
}

// ---------------- x -> bf16 ----------------
__global__ __launch_bounds__(256) void cvt_x_kernel(const float* __restrict__ x,
                                                    unsigned short* __restrict__ xb) {
  int i = blockIdx.x * 256 + threadIdx.x;   // one thread = 8 elements
  const float4* p = reinterpret_cast<const float4*>(x);
  float4 a = p[2 * i], b = p[2 * i + 1];
  uint4 st;
  st.x = (unsigned)f2b(a.x) | ((unsigned)f2b(a.y) << 16);
  st.y = (unsigned)f2b(a.z) | ((unsigned)f2b(a.w) << 16);
  st.z = (unsigned)f2b(b.x) | ((unsigned)f2b(b.y) << 16);
  st.w = (unsigned)f2b(b.z) | ((unsigned)f2b(b.w) << 16);
  reinterpret_cast<uint4*>(xb)[i] = st;
}

// ------- transpose+convert: in [E][R][C] f32 -> out [E][C][R] bf16 -------
__global__ __launch_bounds__(256) void transpose_cvt_kernel(const float* __restrict__ in,
                                                            unsigned short* __restrict__ out,
                                                            int R, int C) {
  __shared__ float tile[64][33];
  int e = blockIdx.z;
  size_t base = (size_t)e * R * C;
  int c0 = blockIdx.x * 32, r0 = blockIdx.y * 64;
  int tx = threadIdx.x & 31, ty = threadIdx.x >> 5;   // 32 x 8
#pragma unroll
  for (int i = 0; i < 64; i += 8)
    tile[ty + i][tx] = in[base + (size_t)(r0 + ty + i) * C + (c0 + tx)];
  __syncthreads();
#pragma unroll
  for (int k = 0; k < 4; k++) {
    int c = ty + k * 8;
    unsigned lo = f2b(tile[2 * tx][c]);
    unsigned hi = f2b(tile[2 * tx + 1][c]);
    *reinterpret_cast<unsigned*>(&out[base + (size_t)(c0 + c) * R + r0 + 2 * tx]) =
        lo | (hi << 16);
  }
}

// ---------------- gw transpose: gwT[e][d] = gw[d*12+e] ----------------
__global__ __launch_bounds__(256) void gwt_kernel(const float* __restrict__ gw,
                                                  float* __restrict__ gwT) {
  int e = blockIdx.x;
#pragma unroll
  for (int i = 0; i < 4; i++) {
    int d = i * 256 + threadIdx.x;
    gwT[e * D_DIM + d] = gw[(size_t)d * E_NUM + e];
  }
}

// ---------------- gating: one wave per 4 tokens, no atomics ----------------
__global__ __launch_bounds__(256) void gating_kernel(const float* __restrict__ x,
                                                     const float* __restrict__ gwT,
                                                     const float* __restrict__ gb,
                                                     int* __restrict__ tk_e,
                                                     float* __restrict__ tk_w) {
  int wv = (blockIdx.x * 256 + threadIdx.x) >> 6;  // global wave id
  int lane = threadIdx.x & 63;
  int n0 = wv * 4;                                  // 4 tokens per wave
  if (n0 >= N_TOK) return;

  const float4* x4 = reinterpret_cast<const float4*>(x);
  const float4* g4 = reinterpret_cast<const float4*>(gwT);

  float acc[4][E_NUM];
#pragma unroll
  for (int t = 0; t < 4; t++)
#pragma unroll
    for (int e = 0; e < E_NUM; e++) acc[t][e] = 0.f;

#pragma unroll
  for (int i = 0; i < 4; i++) {
    float4 xv[4];
#pragma unroll
    for (int t = 0; t < 4; t++) xv[t] = x4[(size_t)(n0 + t) * 256 + i * 64 + lane];
#pragma unroll
    for (int e = 0; e < E_NUM; e++) {
      float4 g = g4[e * 256 + i * 64 + lane];
#pragma unroll
      for (int t = 0; t < 4; t++) {
        acc[t][e] += xv[t].x * g.x + xv[t].y * g.y + xv[t].z * g.z + xv[t].w * g.w;
      }
    }
  }

#pragma unroll
  for (int t = 0; t < 4; t++)
#pragma unroll
    for (int e = 0; e < E_NUM; e++) {
      float v = acc[t][e];
#pragma unroll
      for (int s = 32; s > 0; s >>= 1) v += __shfl_xor(v, s, 64);
      acc[t][e] = v;
    }

#pragma unroll
  for (int t = 0; t < 4; t++) {
    if (lane == t) {
      int n = n0 + t;
      float sc[E_NUM], sm[E_NUM];
      float mx = -1e30f;
#pragma unroll
      for (int e = 0; e < E_NUM; e++) { sc[e] = acc[t][e] + gb[e]; mx = fmaxf(mx, sc[e]); }
      float Z = 0.f;
#pragma unroll
      for (int e = 0; e < E_NUM; e++) { sm[e] = expf(sc[e] - mx); Z += sm[e]; }
      bool used[E_NUM];
#pragma unroll
      for (int e = 0; e < E_NUM; e++) used[e] = false;
      int eid[TOPK]; float p[TOPK]; float wsum = 0.f;
      for (int k = 0; k < TOPK; k++) {
        float best = -1e30f; int bi = 0;
        for (int e = 0; e < E_NUM; e++)
          if (!used[e] && sc[e] > best) { best = sc[e]; bi = e; }  // strict >: ties -> lowest idx
        used[bi] = true; eid[k] = bi; p[k] = sm[bi] / Z; wsum += p[k];
      }
      float inv = 1.f / (wsum + 1e-8f);
      for (int k = 0; k < TOPK; k++) {
        tk_e[n * TOPK + k] = eid[k];
        tk_w[n * TOPK + k] = p[k] * inv;
      }
    }
  }
}

// ------- hist_rank: per-block, per-expert stable ranks via ballot (no atomics) -------
__global__ __launch_bounds__(256) void hist_rank_kernel(const int* __restrict__ tk_e,
                                                        int* __restrict__ lr,
                                                        int* __restrict__ bc) {
  int blk = blockIdx.x, t = threadIdx.x;
  int n = blk * 256 + t;
  int4 te = reinterpret_cast<const int4*>(tk_e)[n];
  int lane = t & 63, w = t >> 6;
  __shared__ int wt[4][E_NUM];
  int r0 = 0, r1 = 0, r2 = 0, r3 = 0;
#pragma unroll
  for (int e = 0; e < E_NUM; e++) {
    int flag = (te.x == e) || (te.y == e) || (te.z == e) || (te.w == e);
    unsigned long long m = __ballot(flag);
    int rw = __popcll(m & ((1ull << lane) - 1ull));
    if (lane == 0) wt[w][e] = __popcll(m);
    if (te.x == e) r0 = rw;
    if (te.y == e) r1 = rw;
    if (te.z == e) r2 = rw;
    if (te.w == e) r3 = rw;
  }
  __syncthreads();
#pragma unroll
  for (int e = 0; e < E_NUM; e++) {
    int base = 0;
#pragma unroll
    for (int w2 = 0; w2 < 4; w2++)
      if (w2 < w) base += wt[w2][e];
    if (te.x == e) r0 += base;
    if (te.y == e) r1 += base;
    if (te.z == e) r2 += base;
    if (te.w == e) r3 += base;
  }
  int4 out; out.x = r0; out.y = r1; out.z = r2; out.w = r3;
  reinterpret_cast<int4*>(lr)[n] = out;
  if (t == 0) {
#pragma unroll
    for (int e = 0; e < E_NUM; e++)
      bc[blk * E_NUM + e] = wt[0][e] + wt[1][e] + wt[2][e] + wt[3][e];
  }
}

// ------- scan2: per-expert totals -> padded poff + per-block bases bb -------
__global__ __launch_bounds__(64) void scan2_kernel(const int* __restrict__ bc,
                                                   int* __restrict__ poff,
                                                   int* __restrict__ bb) {
  int t = threadIdx.x;
  __shared__ int cnte[E_NUM];
  __shared__ int spoff[E_NUM + 1];
  if (t < E_NUM) {
    int s = 0;
#pragma unroll
    for (int b = 0; b < 32; b++) s += bc[b * E_NUM + t];
    cnte[t] = s;
  }
  __syncthreads();
  if (t == 0) {
    int off = 0; spoff[0] = 0;
    for (int e = 0; e < E_NUM; e++) {
      off += ((cnte[e] + 127) >> 7) << 7;
      spoff[e + 1] = off;
    }
  }
  __syncthreads();
  if (t < E_NUM + 1) poff[t] = spoff[t];
  if (t < E_NUM) {
    int run = spoff[t];
    for (int b = 0; b < 32; b++) {
      bb[b * E_NUM + t] = run;
      run += bc[b * E_NUM + t];
    }
  }
}

__global__ __launch_bounds__(256) void fill_pairs_kernel(int* __restrict__ pt) {
  int i = blockIdx.x * 256 + threadIdx.x;
  if (i < PAIR_CAP) pt[i] = 0;
}

// ------- scatter2: pure writes at precomputed positions; lr slot becomes ip -------
__global__ __launch_bounds__(256) void scatter2_kernel(const int* __restrict__ tk_e,
                                                       int* __restrict__ lr_ip,
                                                       const int* __restrict__ bb,
                                                       int* __restrict__ pt) {
  int n = blockIdx.x * 256 + threadIdx.x;
  if (n >= N_TOK) return;
  int blk = n >> 8;
  int4 te = reinterpret_cast<const int4*>(tk_e)[n];
  int4 l4 = reinterpret_cast<const int4*>(lr_ip)[n];
  int p0 = bb[blk * E_NUM + te.x] + l4.x;
  int p1 = bb[blk * E_NUM + te.y] + l4.y;
  int p2 = bb[blk * E_NUM + te.z] + l4.z;
  int p3 = bb[blk * E_NUM + te.w] + l4.w;
  pt[p0] = n; pt[p1] = n; pt[p2] = n; pt[p3] = n;
  int4 ip; ip.x = p0; ip.y = p1; ip.z = p2; ip.w = p3;
  reinterpret_cast<int4*>(lr_ip)[n] = ip;     // overwrite ranks with positions
}

// =================== GEMMs: 128x128 tile, BK=64 (2x BK=32 sub-tiles) ===================
// Round-14 proven body/config (TPC=134/NCH=2/NS=2, best: 969us). Single change:
// gemm1's intra-XCD decode flips to TILE-fastest/colb-outermost. gemm1's B panel
// (8MB/expert) > 4MB L2 thrashes under the A-grouped decode (FETCH 505MB vs 112
// unique); with colb-outer, each (XCD,colb) reads a 256KB/expert B slice ->
// L2-resident, w1t fetched from HBM exactly once. gemm2 keeps A-grouped decode
// (its B panel is 2MB -> L2-resident either way; A-grouping proven, r8: 692->227MB).

// ---------------- GEMM1: h = relu(x[tok] @ W1_e + b1_e), bf16 out ----------------
__global__ __launch_bounds__(256, 4) void gemm1_kernel(
    const unsigned short* __restrict__ xb,    // [N][D] bf16
    const unsigned short* __restrict__ w1t,   // [E][H][D] bf16
    const float* __restrict__ b1,             // [E][H]
    const int* __restrict__ pair_token,
    const int* __restrict__ poff,
    unsigned short* __restrict__ hbuf,        // [TPC*128][H] bf16
    int tile0, int tpc) {
  __shared__ unsigned short As[2][128 * 32];
  __shared__ unsigned short Bs[2][128 * 32];
  // XCD-chunked bijective swizzle (nwg % 8 == 0); TILE fastest within chunk:
  // XCD q owns colb [4q,4q+4); per colb, B slice 256KB/expert stays L2-resident.
  int cpx = gridDim.x >> 3;
  int f = (blockIdx.x & 7) * cpx + (blockIdx.x >> 3);
  int tile = f % tpc;                         // fastest
  int colb = f / tpc;                         // 0..31, outermost

  int t = tile0 + tile;
  int totTiles = poff[E_NUM] >> 7;
  if (t >= totTiles) return;
  int rowg0 = t << 7;
  int e = 0;
#pragma unroll
  for (int i = 1; i < E_NUM; i++) e += (rowg0 >= poff[i]);

  const int tid = threadIdx.x;
  const int lane = tid & 63, wave = tid >> 6;
  const int wm = wave >> 1, wn = wave & 1;
  const int fr = lane & 15, fgq = lane >> 4;

  const int srow = tid >> 2;                              // staging row 0..63
  const int skc = (((tid & 3) ^ ((srow >> 1) & 3)) << 3); // swizzled source chunk (elems)
  int tok0 = pair_token[rowg0 + srow];
  int tok1 = pair_token[rowg0 + 64 + srow];
  const unsigned short* a0 = xb + (size_t)tok0 * D_DIM + skc;
  const unsigned short* a1 = xb + (size_t)tok1 * D_DIM + skc;
  int n0 = colb << 7;
  const unsigned short* wb = w1t + (size_t)e * H_DIM * D_DIM;
  const unsigned short* b0p = wb + (size_t)(n0 + srow) * D_DIM + skc;
  const unsigned short* b1p = wb + (size_t)(n0 + 64 + srow) * D_DIM + skc;

  const int cswz = (fgq ^ ((fr >> 1) & 3)) << 3;
  int aoff[4], boff[4];
#pragma unroll
  for (int mf = 0; mf < 4; mf++) aoff[mf] = (wm * 64 + mf * 16 + fr) * 32 + cswz;
#pragma unroll
  for (int nf = 0; nf < 4; nf++) boff[nf] = (wn * 64 + nf * 16 + fr) * 32 + cswz;

  f32x4 acc[4][4];
#pragma unroll
  for (int i = 0; i < 4; i++)
#pragma unroll
    for (int j = 0; j < 4; j++) acc[i][j] = (f32x4){0.f, 0.f, 0.f, 0.f};

  for (int kt = 0; kt < D_DIM / 64; ++kt) {
    int k0 = kt * 64;
#pragma unroll
    for (int h = 0; h < 2; h++) {
      int kh = k0 + h * 32;
      gload16(a0 + kh, &As[h][tid * 8]);
      gload16(a1 + kh, &As[h][2048 + tid * 8]);
      gload16(b0p + kh, &Bs[h][tid * 8]);
      gload16(b1p + kh, &Bs[h][2048 + tid * 8]);
    }
    __syncthreads();
#pragma unroll
    for (int h = 0; h < 2; h++) {
      bf16x8 af[4], bq[4];
#pragma unroll
      for (int mf = 0; mf < 4; mf++)
        af[mf] = *reinterpret_cast<const bf16x8*>(&As[h][aoff[mf]]);
#pragma unroll
      for (int nf = 0; nf < 4; nf++)
        bq[nf] = *reinterpret_cast<const bf16x8*>(&Bs[h][boff[nf]]);
#pragma unroll
      for (int mf = 0; mf < 4; mf++)
#pragma unroll
        for (int nf = 0; nf < 4; nf++)
          acc[mf][nf] = __builtin_amdgcn_mfma_f32_16x16x32_bf16(af[mf], bq[nf], acc[mf][nf], 0, 0, 0);
    }
    __syncthreads();
  }

  int lrow0 = tile << 7;
#pragma unroll
  for (int nf = 0; nf < 4; nf++) {
    int col = n0 + wn * 64 + nf * 16 + fr;
    float bias = b1[e * H_DIM + col];
#pragma unroll
    for (int mf = 0; mf < 4; mf++) {
      int m = wm * 64 + mf * 16 + fgq * 4;
#pragma unroll
      for (int r = 0; r < 4; r++) {
        float v = fmaxf(acc[mf][nf][r] + bias, 0.f);
        hbuf[(size_t)(lrow0 + m + r) * H_DIM + col] = f2b(v);
      }
    }
  }
}

// ------- GEMM2: youts[z][pair] = h @ W2_e (+b2 on z==0), plain bf16 stores -------
__global__ __launch_bounds__(256, 4) void gemm2_kernel(
    const unsigned short* __restrict__ hbuf,  // [TPC*128][H] bf16
    const unsigned short* __restrict__ w2t,   // [E][O][H] bf16
    const float* __restrict__ b2,             // [E][O]
    const int* __restrict__ poff,
    unsigned short* __restrict__ youts,       // [nsplit][PAIR_CAP][O] bf16
    int tile0, int tpc, int nsplit) {
  __shared__ unsigned short As[2][128 * 32];
  __shared__ unsigned short Bs[2][128 * 32];
  // XCD-chunked swizzle; decode: colb fastest, then z, tile outermost (A-grouped).
  int cpx = gridDim.x >> 3;
  int f = (blockIdx.x & 7) * cpx + (blockIdx.x >> 3);
  int colb = f & 7;                           // 0..7, fastest
  int rest = f >> 3;
  int z = rest % nsplit;
  int tile = rest / nsplit;

  int t = tile0 + tile;
  int totTiles = poff[E_NUM] >> 7;
  if (t >= totTiles) return;
  int rowg0 = t << 7;
  int e = 0;
#pragma unroll
  for (int i = 1; i < E_NUM; i++) e += (rowg0 >= poff[i]);

  const int tid = threadIdx.x;
  const int lane = tid & 63, wave = tid >> 6;
  const int wm = wave >> 1, wn = wave & 1;
  const int fr = lane & 15, fgq = lane >> 4;
  const int kspan = H_DIM / nsplit;
  const int kbase = z * kspan;

  const int srow = tid >> 2;
  const int skc = (((tid & 3) ^ ((srow >> 1) & 3)) << 3);
  int lrowb = tile << 7;
  const unsigned short* a0 = hbuf + (size_t)(lrowb + srow) * H_DIM + kbase + skc;
  const unsigned short* a1 = hbuf + (size_t)(lrowb + 64 + srow) * H_DIM + kbase + skc;
  int n0 = colb << 7;
  const unsigned short* wb = w2t + (size_t)e * O_DIM * H_DIM;
  const unsigned short* b0p = wb + (size_t)(n0 + srow) * H_DIM + kbase + skc;
  const unsigned short* b1p = wb + (size_t)(n0 + 64 + srow) * H_DIM + kbase + skc;

  const int cswz = (fgq ^ ((fr >> 1) & 3)) << 3;
  int aoff[4], boff[4];
#pragma unroll
  for (int mf = 0; mf < 4; mf++) aoff[mf] = (wm * 64 + mf * 16 + fr) * 32 + cswz;
#pragma unroll
  for (int nf = 0; nf < 4; nf++) boff[nf] = (wn * 64 + nf * 16 + fr) * 32 + cswz;

  f32x4 acc[4][4];
#pragma unroll
  for (int i = 0; i < 4; i++)
#pragma unroll
    for (int j = 0; j < 4; j++) acc[i][j] = (f32x4){0.f, 0.f, 0.f, 0.f};

  for (int kt = 0; kt < kspan / 64; ++kt) {
    int k0 = kt * 64;
#pragma unroll
    for (int h = 0; h < 2; h++) {
      int kh = k0 + h * 32;
      gload16(a0 + kh, &As[h][tid * 8]);
      gload16(a1 + kh, &As[h][2048 + tid * 8]);
      gload16(b0p + kh, &Bs[h][tid * 8]);
      gload16(b1p + kh, &Bs[h][2048 + tid * 8]);
    }
    __syncthreads();
#pragma unroll
    for (int h = 0; h < 2; h++) {
      bf16x8 af[4], bq[4];
#pragma unroll
      for (int mf = 0; mf < 4; mf++)
        af[mf] = *reinterpret_cast<const bf16x8*>(&As[h][aoff[mf]]);
#pragma unroll
      for (int nf = 0; nf < 4; nf++)
        bq[nf] = *reinterpret_cast<const bf16x8*>(&Bs[h][boff[nf]]);
#pragma unroll
      for (int mf = 0; mf < 4; mf++)
#pragma unroll
        for (int nf = 0; nf < 4; nf++)
          acc[mf][nf] = __builtin_amdgcn_mfma_f32_16x16x32_bf16(af[mf], bq[nf], acc[mf][nf], 0, 0, 0);
    }
    __syncthreads();
  }

  size_t ybase = (size_t)z * PAIR_CAP;
#pragma unroll
  for (int nf = 0; nf < 4; nf++) {
    int col = n0 + wn * 64 + nf * 16 + fr;
    float bias = (z == 0) ? b2[e * O_DIM + col] : 0.f;   // bias counted once
#pragma unroll
    for (int mf = 0; mf < 4; mf++) {
      int m = wm * 64 + mf * 16 + fgq * 4;
#pragma unroll
      for (int r = 0; r < 4; r++) {
        float v = acc[mf][nf][r] + bias;
        youts[(ybase + rowg0 + m + r) * O_DIM + col] = f2b(v);
      }
    }
  }
}

// ------- reduce: out[n] = sum_k w_k * (y0[p_k] (+ y1[p_k])) -------
static __device__ __forceinline__ void acc8(float* a, const unsigned short* y, float wk) {
  u16x8 v = *reinterpret_cast<const u16x8*>(y);
#pragma unroll
  for (int j = 0; j < 8; j++)
    a[j] += wk * __uint_as_float((unsigned)v[j] << 16);
}

__global__ __launch_bounds__(256) void reduce_kernel(const unsigned short* __restrict__ youts,
                                                     const int* __restrict__ ip,
                                                     const float* __restrict__ tk_w,
                                                     float* __restrict__ out,
                                                     int nsplit) {
  int gid = blockIdx.x * 256 + threadIdx.x;      // N_TOK * 128 threads
  int n = gid >> 7;
  int c0 = (gid & 127) << 3;
  int4 p = reinterpret_cast<const int4*>(ip)[n];
  float4 w = reinterpret_cast<const float4*>(tk_w)[n];
  const size_t zoff = (size_t)PAIR_CAP * O_DIM;
  float a[8];
#pragma unroll
  for (int j = 0; j < 8; j++) a[j] = 0.f;
  {
    const unsigned short* y = youts + (size_t)p.x * O_DIM + c0;
    acc8(a, y, w.x);
    if (nsplit == 2) acc8(a, y + zoff, w.x);
  }
  {
    const unsigned short* y = youts + (size_t)p.y * O_DIM + c0;
    acc8(a, y, w.y);
    if (nsplit == 2) acc8(a, y + zoff, w.y);
  }
  {
    const unsigned short* y = youts + (size_t)p.z * O_DIM + c0;
    acc8(a, y, w.z);
    if (nsplit == 2) acc8(a, y + zoff, w.z);
  }
  {
    const unsigned short* y = youts + (size_t)p.w * O_DIM + c0;
    acc8(a, y, w.w);
    if (nsplit == 2) acc8(a, y + zoff, w.w);
  }
  float* orow = out + (size_t)n * O_DIM + c0;
  float4 o0; o0.x = a[0]; o0.y = a[1]; o0.z = a[2]; o0.w = a[3];
  float4 o1; o1.x = a[4]; o1.y = a[5]; o1.z = a[6]; o1.w = a[7];
  reinterpret_cast<float4*>(orow)[0] = o0;
  reinterpret_cast<float4*>(orow)[1] = o1;
}

extern "C" void kernel_launch(void* const* d_in, const int* in_sizes, int n_in,
                              void* d_out, int out_size, void* d_ws, size_t ws_size,
                              hipStream_t stream) {
  const float* x  = (const float*)d_in[0];
  const float* gw = (const float*)d_in[1];
  const float* gb = (const float*)d_in[2];
  const float* w1 = (const float*)d_in[3];
  const float* b1 = (const float*)d_in[4];
  const float* w2 = (const float*)d_in[5];
  const float* b2 = (const float*)d_in[6];
  float* out = (float*)d_out;

  char* ws = (char*)d_ws;
  size_t off = 0;
  auto alloc = [&](size_t bytes) -> void* {
    void* p = ws + off;
    off = (off + bytes + 255) & ~(size_t)255;
    return p;
  };
  unsigned short* xb   = (unsigned short*)alloc((size_t)N_TOK * D_DIM * 2);
  unsigned short* w1t  = (unsigned short*)alloc((size_t)E_NUM * H_DIM * D_DIM * 2);
  unsigned short* w2t  = (unsigned short*)alloc((size_t)E_NUM * O_DIM * H_DIM * 2);
  float* gwT  = (float*)alloc((size_t)E_NUM * D_DIM * 4);
  int*   tk_e = (int*)alloc((size_t)N_TOK * TOPK * 4);
  float* tk_w = (float*)alloc((size_t)N_TOK * TOPK * 4);
  int*   lr   = (int*)alloc((size_t)N_TOK * TOPK * 4);   // ranks, then pair positions (ip)
  int*   pt   = (int*)alloc((size_t)PAIR_CAP * 4);
  int*   bc   = (int*)alloc(32 * E_NUM * 4);
  int*   bb   = (int*)alloc(32 * E_NUM * 4);
  int*   poff = (int*)alloc(64);

  // Round-14 proven tiers: TPC=134/NCH=2/NS=2 preferred.
  const size_t HB134 = (size_t)134 * 128 * H_DIM * 2;
  const size_t HB67  = (size_t)67 * 128 * H_DIM * 2;
  const size_t YO    = (size_t)PAIR_CAP * O_DIM * 2;
  int TPC, NCH, NS;
  if (ws_size >= off + HB134 + 2 * YO + 1024)      { TPC = 134; NCH = 2; NS = 2; }
  else if (ws_size >= off + HB134 + YO + 1024)     { TPC = 134; NCH = 2; NS = 1; }
  else                                             { TPC = 67;  NCH = 4; NS = 1; }
  unsigned short* hbuf  = (unsigned short*)alloc((size_t)TPC * 128 * H_DIM * 2);
  unsigned short* youts = (unsigned short*)alloc((size_t)NS * YO);
  if (off > ws_size) return;   // workspace too small: fail cleanly

  cvt_x_kernel<<<N_TOK * D_DIM / 8 / 256, 256, 0, stream>>>(x, xb);
  transpose_cvt_kernel<<<dim3(H_DIM / 32, D_DIM / 64, E_NUM), 256, 0, stream>>>(w1, w1t, D_DIM, H_DIM);
  transpose_cvt_kernel<<<dim3(O_DIM / 32, H_DIM / 64, E_NUM), 256, 0, stream>>>(w2, w2t, H_DIM, O_DIM);
  gwt_kernel<<<E_NUM, 256, 0, stream>>>(gw, gwT);
  gating_kernel<<<N_TOK / 16, 256, 0, stream>>>(x, gwT, gb, tk_e, tk_w);
  hist_rank_kernel<<<N_TOK / 256, 256, 0, stream>>>(tk_e, lr, bc);
  scan2_kernel<<<1, 64, 0, stream>>>(bc, poff, bb);
  fill_pairs_kernel<<<(PAIR_CAP + 255) / 256, 256, 0, stream>>>(pt);
  scatter2_kernel<<<N_TOK / 256, 256, 0, stream>>>(tk_e, lr, bb, pt);

  for (int c = 0; c < NCH; c++) {
    int tile0 = c * TPC;
    gemm1_kernel<<<dim3((H_DIM / 128) * TPC), 256, 0, stream>>>(xb, w1t, b1, pt, poff, hbuf, tile0, TPC);
    gemm2_kernel<<<dim3((O_DIM / 128) * TPC * NS), 256, 0, stream>>>(hbuf, w2t, b2, poff, youts, tile0, TPC, NS);
  }
  reduce_kernel<<<N_TOK * (O_DIM / 8) / 256, 256, 0, stream>>>(youts, lr, tk_w, out, NS);
}

// Round 17
// 966.474 us; speedup vs baseline: 1.0547x; 1.0181x over previous
//
#include <hip/hip_runtime.h>
#include <stdint.h>

#define D_DIM 1024
#define H_DIM 4096
#define O_DIM 1024
#define E_NUM 12
#define TOPK 4
#define N_TOK 8192

#define PAIR_CAP 34304          // up to 268 tiles * 128

typedef __bf16 bf16x8 __attribute__((ext_vector_type(8)));
typedef float f32x4 __attribute__((ext_vector_type(4)));
typedef unsigned short u16x8 __attribute__((ext_vector_type(8)));

typedef __attribute__((address_space(3))) unsigned int lds_uint;
typedef __attribute__((address_space(1))) const unsigned int glob_uint;

static __device__ __forceinline__ unsigned short f2b(float f) {
  union { float f; unsigned u; } v; v.f = f;
  unsigned r = v.u + 0x7FFFu + ((v.u >> 16) & 1u);   // RNE
  return (unsigned short)(r >> 16);
}

static __device__ __forceinline__ void gload16(const void* g, void* l) {
  __builtin_amdgcn_global_load_lds((glob_uint*)g, (lds_uint*)l, 16, 0, 0);
}

// ---------------- x -> bf16 ----------------
__global__ __launch_bounds__(256) void cvt_x_kernel(const float* __restrict__ x,
                                                    unsigned short* __restrict__ xb) {
  int i = blockIdx.x * 256 + threadIdx.x;   // one thread = 8 elements
  const float4* p = reinterpret_cast<const float4*>(x);
  float4 a = p[2 * i], b = p[2 * i + 1];
  uint4 st;
  st.x = (unsigned)f2b(a.x) | ((unsigned)f2b(a.y) << 16);
  st.y = (unsigned)f2b(a.z) | ((unsigned)f2b(a.w) << 16);
  st.z = (unsigned)f2b(b.x) | ((unsigned)f2b(b.y) << 16);
  st.w = (unsigned)f2b(b.z) | ((unsigned)f2b(b.w) << 16);
  reinterpret_cast<uint4*>(xb)[i] = st;
}

// ------- transpose+convert: in [E][R][C] f32 -> out [E][C][R] bf16 -------
__global__ __launch_bounds__(256) void transpose_cvt_kernel(const float* __restrict__ in,
                                                            unsigned short* __restrict__ out,
                                                            int R, int C) {
  __shared__ float tile[64][33];
  int e = blockIdx.z;
  size_t base = (size_t)e * R * C;
  int c0 = blockIdx.x * 32, r0 = blockIdx.y * 64;
  int tx = threadIdx.x & 31, ty = threadIdx.x >> 5;   // 32 x 8
#pragma unroll
  for (int i = 0; i < 64; i += 8)
    tile[ty + i][tx] = in[base + (size_t)(r0 + ty + i) * C + (c0 + tx)];
  __syncthreads();
#pragma unroll
  for (int k = 0; k < 4; k++) {
    int c = ty + k * 8;
    unsigned lo = f2b(tile[2 * tx][c]);
    unsigned hi = f2b(tile[2 * tx + 1][c]);
    *reinterpret_cast<unsigned*>(&out[base + (size_t)(c0 + c) * R + r0 + 2 * tx]) =
        lo | (hi << 16);
  }
}

// ---------------- gw transpose: gwT[e][d] = gw[d*12+e] ----------------
__global__ __launch_bounds__(256) void gwt_kernel(const float* __restrict__ gw,
                                                  float* __restrict__ gwT) {
  int e = blockIdx.x;
#pragma unroll
  for (int i = 0; i < 4; i++) {
    int d = i * 256 + threadIdx.x;
    gwT[e * D_DIM + d] = gw[(size_t)d * E_NUM + e];
  }
}

// ---------------- gating: one wave per 4 tokens, no atomics ----------------
__global__ __launch_bounds__(256) void gating_kernel(const float* __restrict__ x,
                                                     const float* __restrict__ gwT,
                                                     const float* __restrict__ gb,
                                                     int* __restrict__ tk_e,
                                                     float* __restrict__ tk_w) {
  int wv = (blockIdx.x * 256 + threadIdx.x) >> 6;  // global wave id
  int lane = threadIdx.x & 63;
  int n0 = wv * 4;                                  // 4 tokens per wave
  if (n0 >= N_TOK) return;

  const float4* x4 = reinterpret_cast<const float4*>(x);
  const float4* g4 = reinterpret_cast<const float4*>(gwT);

  float acc[4][E_NUM];
#pragma unroll
  for (int t = 0; t < 4; t++)
#pragma unroll
    for (int e = 0; e < E_NUM; e++) acc[t][e] = 0.f;

#pragma unroll
  for (int i = 0; i < 4; i++) {
    float4 xv[4];
#pragma unroll
    for (int t = 0; t < 4; t++) xv[t] = x4[(size_t)(n0 + t) * 256 + i * 64 + lane];
#pragma unroll
    for (int e = 0; e < E_NUM; e++) {
      float4 g = g4[e * 256 + i * 64 + lane];
#pragma unroll
      for (int t = 0; t < 4; t++) {
        acc[t][e] += xv[t].x * g.x + xv[t].y * g.y + xv[t].z * g.z + xv[t].w * g.w;
      }
    }
  }

#pragma unroll
  for (int t = 0; t < 4; t++)
#pragma unroll
    for (int e = 0; e < E_NUM; e++) {
      float v = acc[t][e];
#pragma unroll
      for (int s = 32; s > 0; s >>= 1) v += __shfl_xor(v, s, 64);
      acc[t][e] = v;
    }

#pragma unroll
  for (int t = 0; t < 4; t++) {
    if (lane == t) {
      int n = n0 + t;
      float sc[E_NUM], sm[E_NUM];
      float mx = -1e30f;
#pragma unroll
      for (int e = 0; e < E_NUM; e++) { sc[e] = acc[t][e] + gb[e]; mx = fmaxf(mx, sc[e]); }
      float Z = 0.f;
#pragma unroll
      for (int e = 0; e < E_NUM; e++) { sm[e] = expf(sc[e] - mx); Z += sm[e]; }
      bool used[E_NUM];
#pragma unroll
      for (int e = 0; e < E_NUM; e++) used[e] = false;
      int eid[TOPK]; float p[TOPK]; float wsum = 0.f;
      for (int k = 0; k < TOPK; k++) {
        float best = -1e30f; int bi = 0;
        for (int e = 0; e < E_NUM; e++)
          if (!used[e] && sc[e] > best) { best = sc[e]; bi = e; }  // strict >: ties -> lowest idx
        used[bi] = true; eid[k] = bi; p[k] = sm[bi] / Z; wsum += p[k];
      }
      float inv = 1.f / (wsum + 1e-8f);
      for (int k = 0; k < TOPK; k++) {
        tk_e[n * TOPK + k] = eid[k];
        tk_w[n * TOPK + k] = p[k] * inv;
      }
    }
  }
}

// ------- hist_rank: per-block, per-expert stable ranks via ballot (no atomics) -------
__global__ __launch_bounds__(256) void hist_rank_kernel(const int* __restrict__ tk_e,
                                                        int* __restrict__ lr,
                                                        int* __restrict__ bc) {
  int blk = blockIdx.x, t = threadIdx.x;
  int n = blk * 256 + t;
  int4 te = reinterpret_cast<const int4*>(tk_e)[n];
  int lane = t & 63, w = t >> 6;
  __shared__ int wt[4][E_NUM];
  int r0 = 0, r1 = 0, r2 = 0, r3 = 0;
#pragma unroll
  for (int e = 0; e < E_NUM; e++) {
    int flag = (te.x == e) || (te.y == e) || (te.z == e) || (te.w == e);
    unsigned long long m = __ballot(flag);
    int rw = __popcll(m & ((1ull << lane) - 1ull));
    if (lane == 0) wt[w][e] = __popcll(m);
    if (te.x == e) r0 = rw;
    if (te.y == e) r1 = rw;
    if (te.z == e) r2 = rw;
    if (te.w == e) r3 = rw;
  }
  __syncthreads();
#pragma unroll
  for (int e = 0; e < E_NUM; e++) {
    int base = 0;
#pragma unroll
    for (int w2 = 0; w2 < 4; w2++)
      if (w2 < w) base += wt[w2][e];
    if (te.x == e) r0 += base;
    if (te.y == e) r1 += base;
    if (te.z == e) r2 += base;
    if (te.w == e) r3 += base;
  }
  int4 out; out.x = r0; out.y = r1; out.z = r2; out.w = r3;
  reinterpret_cast<int4*>(lr)[n] = out;
  if (t == 0) {
#pragma unroll
    for (int e = 0; e < E_NUM; e++)
      bc[blk * E_NUM + e] = wt[0][e] + wt[1][e] + wt[2][e] + wt[3][e];
  }
}

// ------- scan2: per-expert totals -> padded poff + per-block bases bb -------
__global__ __launch_bounds__(64) void scan2_kernel(const int* __restrict__ bc,
                                                   int* __restrict__ poff,
                                                   int* __restrict__ bb) {
  int t = threadIdx.x;
  __shared__ int cnte[E_NUM];
  __shared__ int spoff[E_NUM + 1];
  if (t < E_NUM) {
    int s = 0;
#pragma unroll
    for (int b = 0; b < 32; b++) s += bc[b * E_NUM + t];
    cnte[t] = s;
  }
  __syncthreads();
  if (t == 0) {
    int off = 0; spoff[0] = 0;
    for (int e = 0; e < E_NUM; e++) {
      off += ((cnte[e] + 127) >> 7) << 7;
      spoff[e + 1] = off;
    }
  }
  __syncthreads();
  if (t < E_NUM + 1) poff[t] = spoff[t];
  if (t < E_NUM) {
    int run = spoff[t];
    for (int b = 0; b < 32; b++) {
      bb[b * E_NUM + t] = run;
      run += bc[b * E_NUM + t];
    }
  }
}

__global__ __launch_bounds__(256) void fill_pairs_kernel(int* __restrict__ pt) {
  int i = blockIdx.x * 256 + threadIdx.x;
  if (i < PAIR_CAP) pt[i] = 0;
}

// ------- scatter2: pure writes at precomputed positions; lr slot becomes ip -------
__global__ __launch_bounds__(256) void scatter2_kernel(const int* __restrict__ tk_e,
                                                       int* __restrict__ lr_ip,
                                                       const int* __restrict__ bb,
                                                       int* __restrict__ pt) {
  int n = blockIdx.x * 256 + threadIdx.x;
  if (n >= N_TOK) return;
  int blk = n >> 8;
  int4 te = reinterpret_cast<const int4*>(tk_e)[n];
  int4 l4 = reinterpret_cast<const int4*>(lr_ip)[n];
  int p0 = bb[blk * E_NUM + te.x] + l4.x;
  int p1 = bb[blk * E_NUM + te.y] + l4.y;
  int p2 = bb[blk * E_NUM + te.z] + l4.z;
  int p3 = bb[blk * E_NUM + te.w] + l4.w;
  pt[p0] = n; pt[p1] = n; pt[p2] = n; pt[p3] = n;
  int4 ip; ip.x = p0; ip.y = p1; ip.z = p2; ip.w = p3;
  reinterpret_cast<int4*>(lr_ip)[n] = ip;     // overwrite ranks with positions
}

// =================== GEMMs: 128x128 tile, BK=64 (2x BK=32 sub-tiles) ===================
// Round-14 configuration verbatim (best measured: 969us). A-grouped XCD decode in
// both GEMMs (colb fastest within XCD chunk). r15 (L3 chunking) and r16 (B-slice
// decode) both regressed and are reverted; gemm1's residual ~4.5x fetch is
// write-allocation interference from hbuf streaming, not block-order-fixable.

// ---------------- GEMM1: h = relu(x[tok] @ W1_e + b1_e), bf16 out ----------------
__global__ __launch_bounds__(256, 4) void gemm1_kernel(
    const unsigned short* __restrict__ xb,    // [N][D] bf16
    const unsigned short* __restrict__ w1t,   // [E][H][D] bf16
    const float* __restrict__ b1,             // [E][H]
    const int* __restrict__ pair_token,
    const int* __restrict__ poff,
    unsigned short* __restrict__ hbuf,        // [TPC*128][H] bf16
    int tile0, int tpc) {
  __shared__ unsigned short As[2][128 * 32];
  __shared__ unsigned short Bs[2][128 * 32];
  // XCD-chunked bijective swizzle (nwg % 8 == 0); colb fastest within chunk
  int cpx = gridDim.x >> 3;
  int f = (blockIdx.x & 7) * cpx + (blockIdx.x >> 3);
  int colb = f & 31;                          // 0..31, fastest
  int tile = f >> 5;

  int t = tile0 + tile;
  int totTiles = poff[E_NUM] >> 7;
  if (t >= totTiles) return;
  int rowg0 = t << 7;
  int e = 0;
#pragma unroll
  for (int i = 1; i < E_NUM; i++) e += (rowg0 >= poff[i]);

  const int tid = threadIdx.x;
  const int lane = tid & 63, wave = tid >> 6;
  const int wm = wave >> 1, wn = wave & 1;
  const int fr = lane & 15, fgq = lane >> 4;

  const int srow = tid >> 2;                              // staging row 0..63
  const int skc = (((tid & 3) ^ ((srow >> 1) & 3)) << 3); // swizzled source chunk (elems)
  int tok0 = pair_token[rowg0 + srow];
  int tok1 = pair_token[rowg0 + 64 + srow];
  const unsigned short* a0 = xb + (size_t)tok0 * D_DIM + skc;
  const unsigned short* a1 = xb + (size_t)tok1 * D_DIM + skc;
  int n0 = colb << 7;
  const unsigned short* wb = w1t + (size_t)e * H_DIM * D_DIM;
  const unsigned short* b0p = wb + (size_t)(n0 + srow) * D_DIM + skc;
  const unsigned short* b1p = wb + (size_t)(n0 + 64 + srow) * D_DIM + skc;

  const int cswz = (fgq ^ ((fr >> 1) & 3)) << 3;
  int aoff[4], boff[4];
#pragma unroll
  for (int mf = 0; mf < 4; mf++) aoff[mf] = (wm * 64 + mf * 16 + fr) * 32 + cswz;
#pragma unroll
  for (int nf = 0; nf < 4; nf++) boff[nf] = (wn * 64 + nf * 16 + fr) * 32 + cswz;

  f32x4 acc[4][4];
#pragma unroll
  for (int i = 0; i < 4; i++)
#pragma unroll
    for (int j = 0; j < 4; j++) acc[i][j] = (f32x4){0.f, 0.f, 0.f, 0.f};

  for (int kt = 0; kt < D_DIM / 64; ++kt) {
    int k0 = kt * 64;
#pragma unroll
    for (int h = 0; h < 2; h++) {
      int kh = k0 + h * 32;
      gload16(a0 + kh, &As[h][tid * 8]);
      gload16(a1 + kh, &As[h][2048 + tid * 8]);
      gload16(b0p + kh, &Bs[h][tid * 8]);
      gload16(b1p + kh, &Bs[h][2048 + tid * 8]);
    }
    __syncthreads();
#pragma unroll
    for (int h = 0; h < 2; h++) {
      bf16x8 af[4], bq[4];
#pragma unroll
      for (int mf = 0; mf < 4; mf++)
        af[mf] = *reinterpret_cast<const bf16x8*>(&As[h][aoff[mf]]);
#pragma unroll
      for (int nf = 0; nf < 4; nf++)
        bq[nf] = *reinterpret_cast<const bf16x8*>(&Bs[h][boff[nf]]);
#pragma unroll
      for (int mf = 0; mf < 4; mf++)
#pragma unroll
        for (int nf = 0; nf < 4; nf++)
          acc[mf][nf] = __builtin_amdgcn_mfma_f32_16x16x32_bf16(af[mf], bq[nf], acc[mf][nf], 0, 0, 0);
    }
    __syncthreads();
  }

  int lrow0 = tile << 7;
#pragma unroll
  for (int nf = 0; nf < 4; nf++) {
    int col = n0 + wn * 64 + nf * 16 + fr;
    float bias = b1[e * H_DIM + col];
#pragma unroll
    for (int mf = 0; mf < 4; mf++) {
      int m = wm * 64 + mf * 16 + fgq * 4;
#pragma unroll
      for (int r = 0; r < 4; r++) {
        float v = fmaxf(acc[mf][nf][r] + bias, 0.f);
        hbuf[(size_t)(lrow0 + m + r) * H_DIM + col] = f2b(v);
      }
    }
  }
}

// ------- GEMM2: youts[z][pair] = h @ W2_e (+b2 on z==0), plain bf16 stores -------
__global__ __launch_bounds__(256, 4) void gemm2_kernel(
    const unsigned short* __restrict__ hbuf,  // [TPC*128][H] bf16
    const unsigned short* __restrict__ w2t,   // [E][O][H] bf16
    const float* __restrict__ b2,             // [E][O]
    const int* __restrict__ poff,
    unsigned short* __restrict__ youts,       // [nsplit][PAIR_CAP][O] bf16
    int tile0, int tpc, int nsplit) {
  __shared__ unsigned short As[2][128 * 32];
  __shared__ unsigned short Bs[2][128 * 32];
  // XCD-chunked swizzle; decode: colb fastest, then z, tile outermost (A-grouped).
  int cpx = gridDim.x >> 3;
  int f = (blockIdx.x & 7) * cpx + (blockIdx.x >> 3);
  int colb = f & 7;                           // 0..7, fastest
  int rest = f >> 3;
  int z = rest % nsplit;
  int tile = rest / nsplit;

  int t = tile0 + tile;
  int totTiles = poff[E_NUM] >> 7;
  if (t >= totTiles) return;
  int rowg0 = t << 7;
  int e = 0;
#pragma unroll
  for (int i = 1; i < E_NUM; i++) e += (rowg0 >= poff[i]);

  const int tid = threadIdx.x;
  const int lane = tid & 63, wave = tid >> 6;
  const int wm = wave >> 1, wn = wave & 1;
  const int fr = lane & 15, fgq = lane >> 4;
  const int kspan = H_DIM / nsplit;
  const int kbase = z * kspan;

  const int srow = tid >> 2;
  const int skc = (((tid & 3) ^ ((srow >> 1) & 3)) << 3);
  int lrowb = tile << 7;
  const unsigned short* a0 = hbuf + (size_t)(lrowb + srow) * H_DIM + kbase + skc;
  const unsigned short* a1 = hbuf + (size_t)(lrowb + 64 + srow) * H_DIM + kbase + skc;
  int n0 = colb << 7;
  const unsigned short* wb = w2t + (size_t)e * O_DIM * H_DIM;
  const unsigned short* b0p = wb + (size_t)(n0 + srow) * H_DIM + kbase + skc;
  const unsigned short* b1p = wb + (size_t)(n0 + 64 + srow) * H_DIM + kbase + skc;

  const int cswz = (fgq ^ ((fr >> 1) & 3)) << 3;
  int aoff[4], boff[4];
#pragma unroll
  for (int mf = 0; mf < 4; mf++) aoff[mf] = (wm * 64 + mf * 16 + fr) * 32 + cswz;
#pragma unroll
  for (int nf = 0; nf < 4; nf++) boff[nf] = (wn * 64 + nf * 16 + fr) * 32 + cswz;

  f32x4 acc[4][4];
#pragma unroll
  for (int i = 0; i < 4; i++)
#pragma unroll
    for (int j = 0; j < 4; j++) acc[i][j] = (f32x4){0.f, 0.f, 0.f, 0.f};

  for (int kt = 0; kt < kspan / 64; ++kt) {
    int k0 = kt * 64;
#pragma unroll
    for (int h = 0; h < 2; h++) {
      int kh = k0 + h * 32;
      gload16(a0 + kh, &As[h][tid * 8]);
      gload16(a1 + kh, &As[h][2048 + tid * 8]);
      gload16(b0p + kh, &Bs[h][tid * 8]);
      gload16(b1p + kh, &Bs[h][2048 + tid * 8]);
    }
    __syncthreads();
#pragma unroll
    for (int h = 0; h < 2; h++) {
      bf16x8 af[4], bq[4];
#pragma unroll
      for (int mf = 0; mf < 4; mf++)
        af[mf] = *reinterpret_cast<const bf16x8*>(&As[h][aoff[mf]]);
#pragma unroll
      for (int nf = 0; nf < 4; nf++)
        bq[nf] = *reinterpret_cast<const bf16x8*>(&Bs[h][boff[nf]]);
#pragma unroll
      for (int mf = 0; mf < 4; mf++)
#pragma unroll
        for (int nf = 0; nf < 4; nf++)
          acc[mf][nf] = __builtin_amdgcn_mfma_f32_16x16x32_bf16(af[mf], bq[nf], acc[mf][nf], 0, 0, 0);
    }
    __syncthreads();
  }

  size_t ybase = (size_t)z * PAIR_CAP;
#pragma unroll
  for (int nf = 0; nf < 4; nf++) {
    int col = n0 + wn * 64 + nf * 16 + fr;
    float bias = (z == 0) ? b2[e * O_DIM + col] : 0.f;   // bias counted once
#pragma unroll
    for (int mf = 0; mf < 4; mf++) {
      int m = wm * 64 + mf * 16 + fgq * 4;
#pragma unroll
      for (int r = 0; r < 4; r++) {
        float v = acc[mf][nf][r] + bias;
        youts[(ybase + rowg0 + m + r) * O_DIM + col] = f2b(v);
      }
    }
  }
}

// ------- reduce: out[n] = sum_k w_k * (y0[p_k] (+ y1[p_k])) -------
static __device__ __forceinline__ void acc8(float* a, const unsigned short* y, float wk) {
  u16x8 v = *reinterpret_cast<const u16x8*>(y);
#pragma unroll
  for (int j = 0; j < 8; j++)
    a[j] += wk * __uint_as_float((unsigned)v[j] << 16);
}

__global__ __launch_bounds__(256) void reduce_kernel(const unsigned short* __restrict__ youts,
                                                     const int* __restrict__ ip,
                                                     const float* __restrict__ tk_w,
                                                     float* __restrict__ out,
                                                     int nsplit) {
  int gid = blockIdx.x * 256 + threadIdx.x;      // N_TOK * 128 threads
  int n = gid >> 7;
  int c0 = (gid & 127) << 3;
  int4 p = reinterpret_cast<const int4*>(ip)[n];
  float4 w = reinterpret_cast<const float4*>(tk_w)[n];
  const size_t zoff = (size_t)PAIR_CAP * O_DIM;
  float a[8];
#pragma unroll
  for (int j = 0; j < 8; j++) a[j] = 0.f;
  {
    const unsigned short* y = youts + (size_t)p.x * O_DIM + c0;
    acc8(a, y, w.x);
    if (nsplit == 2) acc8(a, y + zoff, w.x);
  }
  {
    const unsigned short* y = youts + (size_t)p.y * O_DIM + c0;
    acc8(a, y, w.y);
    if (nsplit == 2) acc8(a, y + zoff, w.y);
  }
  {
    const unsigned short* y = youts + (size_t)p.z * O_DIM + c0;
    acc8(a, y, w.z);
    if (nsplit == 2) acc8(a, y + zoff, w.z);
  }
  {
    const unsigned short* y = youts + (size_t)p.w * O_DIM + c0;
    acc8(a, y, w.w);
    if (nsplit == 2) acc8(a, y + zoff, w.w);
  }
  float* orow = out + (size_t)n * O_DIM + c0;
  float4 o0; o0.x = a[0]; o0.y = a[1]; o0.z = a[2]; o0.w = a[3];
  float4 o1; o1.x = a[4]; o1.y = a[5]; o1.z = a[6]; o1.w = a[7];
  reinterpret_cast<float4*>(orow)[0] = o0;
  reinterpret_cast<float4*>(orow)[1] = o1;
}

extern "C" void kernel_launch(void* const* d_in, const int* in_sizes, int n_in,
                              void* d_out, int out_size, void* d_ws, size_t ws_size,
                              hipStream_t stream) {
  const float* x  = (const float*)d_in[0];
  const float* gw = (const float*)d_in[1];
  const float* gb = (const float*)d_in[2];
  const float* w1 = (const float*)d_in[3];
  const float* b1 = (const float*)d_in[4];
  const float* w2 = (const float*)d_in[5];
  const float* b2 = (const float*)d_in[6];
  float* out = (float*)d_out;

  char* ws = (char*)d_ws;
  size_t off = 0;
  auto alloc = [&](size_t bytes) -> void* {
    void* p = ws + off;
    off = (off + bytes + 255) & ~(size_t)255;
    return p;
  };
  unsigned short* xb   = (unsigned short*)alloc((size_t)N_TOK * D_DIM * 2);
  unsigned short* w1t  = (unsigned short*)alloc((size_t)E_NUM * H_DIM * D_DIM * 2);
  unsigned short* w2t  = (unsigned short*)alloc((size_t)E_NUM * O_DIM * H_DIM * 2);
  float* gwT  = (float*)alloc((size_t)E_NUM * D_DIM * 4);
  int*   tk_e = (int*)alloc((size_t)N_TOK * TOPK * 4);
  float* tk_w = (float*)alloc((size_t)N_TOK * TOPK * 4);
  int*   lr   = (int*)alloc((size_t)N_TOK * TOPK * 4);   // ranks, then pair positions (ip)
  int*   pt   = (int*)alloc((size_t)PAIR_CAP * 4);
  int*   bc   = (int*)alloc(32 * E_NUM * 4);
  int*   bb   = (int*)alloc(32 * E_NUM * 4);
  int*   poff = (int*)alloc(64);

  // Round-14 proven tiers: TPC=134/NCH=2/NS=2 preferred.
  const size_t HB134 = (size_t)134 * 128 * H_DIM * 2;
  const size_t HB67  = (size_t)67 * 128 * H_DIM * 2;
  const size_t YO    = (size_t)PAIR_CAP * O_DIM * 2;
  int TPC, NCH, NS;
  if (ws_size >= off + HB134 + 2 * YO + 1024)      { TPC = 134; NCH = 2; NS = 2; }
  else if (ws_size >= off + HB134 + YO + 1024)     { TPC = 134; NCH = 2; NS = 1; }
  else                                             { TPC = 67;  NCH = 4; NS = 1; }
  unsigned short* hbuf  = (unsigned short*)alloc((size_t)TPC * 128 * H_DIM * 2);
  unsigned short* youts = (unsigned short*)alloc((size_t)NS * YO);
  if (off > ws_size) return;   // workspace too small: fail cleanly

  cvt_x_kernel<<<N_TOK * D_DIM / 8 / 256, 256, 0, stream>>>(x, xb);
  transpose_cvt_kernel<<<dim3(H_DIM / 32, D_DIM / 64, E_NUM), 256, 0, stream>>>(w1, w1t, D_DIM, H_DIM);
  transpose_cvt_kernel<<<dim3(O_DIM / 32, H_DIM / 64, E_NUM), 256, 0, stream>>>(w2, w2t, H_DIM, O_DIM);
  gwt_kernel<<<E_NUM, 256, 0, stream>>>(gw, gwT);
  gating_kernel<<<N_TOK / 16, 256, 0, stream>>>(x, gwT, gb, tk_e, tk_w);
  hist_rank_kernel<<<N_TOK / 256, 256, 0, stream>>>(tk_e, lr, bc);
  scan2_kernel<<<1, 64, 0, stream>>>(bc, poff, bb);
  fill_pairs_kernel<<<(PAIR_CAP + 255) / 256, 256, 0, stream>>>(pt);
  scatter2_kernel<<<N_TOK / 256, 256, 0, stream>>>(tk_e, lr, bb, pt);

  for (int c = 0; c < NCH; c++) {
    int tile0 = c * TPC;
    gemm1_kernel<<<dim3((H_DIM / 128) * TPC), 256, 0, stream>>>(xb, w1t, b1, pt, poff, hbuf, tile0, TPC);
    gemm2_kernel<<<dim3((O_DIM / 128) * TPC * NS), 256, 0, stream>>>(hbuf, w2t, b2, poff, youts, tile0, TPC, NS);
  }
  reduce_kernel<<<N_TOK * (O_DIM / 8) / 256, 256, 0, stream>>>(youts, lr, tk_w, out, NS);
}